// Round 7
// baseline (556.644 us; speedup 1.0000x reference)
//
#include <hip/hip_runtime.h>

// Problem constants (fixed by reference)
#define NN 50000      // nodes
#define NE 800000     // edges
#define DD 256        // node feat dim
#define GFEAT 200     // graph feat dim
#define NG 512        // graphs

typedef __bf16 bf16;
typedef bf16 bf16x4 __attribute__((ext_vector_type(4)));
typedef bf16 bf16x8 __attribute__((ext_vector_type(8)));
typedef float f32x4 __attribute__((ext_vector_type(4)));

// async global->LDS, 16B per lane. HW dest = wave-uniform base + lane*16.
__device__ __forceinline__ void gl_lds16(const bf16* g, bf16* l) {
    __builtin_amdgcn_global_load_lds(
        (const __attribute__((address_space(1))) uint32_t*)(g),
        (__attribute__((address_space(3))) uint32_t*)(l), 16, 0, 0);
}

// BK=64 LDS tile [128][64]; 16B chunk c holds global chunk c^((row>>1)&7)
__device__ __forceinline__ bf16x8 frag_ld64(const bf16* s, int R, int C) {
    return *(const bf16x8*)&s[R * 64 + ((C ^ ((R >> 1) & 7)) << 3)];
}

// stage one 128x64 bf16 tile (16KB) via 4 x gl_lds16/thread, swizzled source
__device__ __forceinline__ void stage_tile(const bf16* src, bf16* dst,
                                           int base_row, int maxrow, int k0, int t) {
#pragma unroll
    for (int r = 0; r < 4; r++) {
        int flat = r * 256 + t;
        int fr = flat >> 3, fc = flat & 7;
        int fcg = fc ^ ((fr >> 1) & 7);
        int row = base_row + fr;
        if (row > maxrow) row = maxrow;
        gl_lds16(&src[(size_t)row * 256 + k0 + fcg * 8], &dst[flat * 8]);
    }
}

#define EPI_STRIDE 136   // bf16 elems; 272 B row stride (16B-aligned, bank-shift 4/row)

// ---------------------------------------------------------------------------
// weight conversion: fp32 [256][N] -> bf16 [n][k] transposed, zero-padded.
// 64x64 LDS-transpose tiles: coalesced reads AND writes (old version had
// 1KB-stride reads = 16x fetch amplification).
// grid (8 mats * 16 tiles), 256 threads.
// ---------------------------------------------------------------------------
__global__ __launch_bounds__(256) void conv_w8t_kernel(
    const float* __restrict__ w0, const float* __restrict__ w1,
    const float* __restrict__ w2, const float* __restrict__ w3,
    const float* __restrict__ w4, const float* __restrict__ w5,
    const float* __restrict__ w6, const float* __restrict__ w7,
    bf16* __restrict__ out_base) {
    const float* ws[8] = {w0, w1, w2, w3, w4, w5, w6, w7};
    const int Ns[8] = {DD, DD, DD, GFEAT, DD, DD, DD, GFEAT};
    const int m = blockIdx.x >> 4;
    const int tile = blockIdx.x & 15;
    const int k0 = (tile >> 2) * 64, n0 = (tile & 3) * 64;
    const float* in = ws[m];
    const int N = Ns[m];
    const int t = threadIdx.x;
    __shared__ float ts[64][65];
#pragma unroll
    for (int r = 0; r < 16; r++) {
        int dk = r * 4 + (t >> 6), dn = t & 63;
        int n = n0 + dn;
        ts[dk][dn] = (n < N) ? in[(k0 + dk) * N + n] : 0.f;
    }
    __syncthreads();
#pragma unroll
    for (int r = 0; r < 16; r++) {
        int dn = r * 4 + (t >> 6), dk = t & 63;
        out_base[(size_t)m * 65536 + (size_t)(n0 + dn) * 256 + k0 + dk] = (bf16)ts[dk][dn];
    }
}

__global__ __launch_bounds__(256) void zero_g_kernel(float* __restrict__ G0,
                                                     float* __restrict__ G1) {
    float* G = blockIdx.y ? G1 : G0;
    int i = blockIdx.x * 256 + threadIdx.x;
    if (i < NG * GFEAT) G[i] = 0.f;
}

// ---------------------------------------------------------------------------
// CSR build: two-level counting sort, zero global atomics, O(1) reads/edge.
// ---------------------------------------------------------------------------
#define NBKT   128
#define NPB    391            // ceil(NN / NBKT); 128*391 = 50048
#define NCHUNK 256
#define CE     ((NE + NCHUNK - 1) / NCHUNK)   // 3125 edges per chunk

__global__ __launch_bounds__(256) void csr_coarse_hist_kernel(
    const int* __restrict__ d0, const int* __restrict__ d1,
    int* __restrict__ cnt0, int* __restrict__ cnt1) {
    const int blk = blockIdx.x, t = threadIdx.x;
    const int* dst = blockIdx.y ? d1 : d0;
    int* cnt = blockIdx.y ? cnt1 : cnt0;
    __shared__ int hist[NBKT];
    if (t < NBKT) hist[t] = 0;
    __syncthreads();
    const int e0 = blk * CE;
    const int e1 = (e0 + CE < NE) ? e0 + CE : NE;
    for (int e = e0 + t; e < e1; e += 256)
        atomicAdd(&hist[dst[e] / NPB], 1);
    __syncthreads();
    if (t < NBKT) cnt[t * NCHUNK + blk] = hist[t];   // bucket-major
}

__global__ __launch_bounds__(1024) void csr_scan_kernel(
    int* __restrict__ cnt0, int* __restrict__ cnt1,
    int* __restrict__ offs0, int* __restrict__ offs1) {
    int* cnt = blockIdx.y ? cnt1 : cnt0;
    const int t = threadIdx.x;
    const int PER = (NBKT * NCHUNK) / 1024;   // 32
    int v[PER];
    int sum = 0;
    const int base = t * PER;
#pragma unroll
    for (int i = 0; i < PER; i += 4) {
        int4 q = *(const int4*)&cnt[base + i];
        v[i] = q.x; v[i + 1] = q.y; v[i + 2] = q.z; v[i + 3] = q.w;
        sum += q.x + q.y + q.z + q.w;
    }
    __shared__ int s[1024];
    s[t] = sum;
    __syncthreads();
    for (int off = 1; off < 1024; off <<= 1) {
        int a = (t >= off) ? s[t - off] : 0;
        __syncthreads();
        s[t] += a;
        __syncthreads();
    }
    int run = s[t] - sum;   // exclusive prefix of this thread's chunk
#pragma unroll
    for (int i = 0; i < PER; i++) { int c = v[i]; cnt[base + i] = run; run += c; }
    if (t == 0) (blockIdx.y ? offs1 : offs0)[NN] = NE;
}

__global__ __launch_bounds__(256) void csr_partition_kernel(
    const int* __restrict__ sA, const int* __restrict__ sB,
    const int* __restrict__ d0, const int* __restrict__ d1,
    const int* __restrict__ cnt0, const int* __restrict__ cnt1,
    int2* __restrict__ eb0, int2* __restrict__ eb1) {
    const int blk = blockIdx.x, t = threadIdx.x;
    const int* src = blockIdx.y ? sB : sA;
    const int* dst = blockIdx.y ? d1 : d0;
    const int* cnt = blockIdx.y ? cnt1 : cnt0;
    int2* eb = blockIdx.y ? eb1 : eb0;
    __shared__ int cur[NBKT];
    if (t < NBKT) cur[t] = cnt[t * NCHUNK + blk];   // this chunk's start in each bucket
    __syncthreads();
    const int e0 = blk * CE;
    const int e1 = (e0 + CE < NE) ? e0 + CE : NE;
    for (int e = e0 + t; e < e1; e += 256) {
        int d = dst[e], s = src[e];
        int pos = atomicAdd(&cur[d / NPB], 1);      // LDS atomic, range disjoint per block
        eb[pos] = make_int2(s, d);
    }
}

__global__ __launch_bounds__(512) void csr_bucket_sort_kernel(
    const int* __restrict__ cnt0, const int* __restrict__ cnt1,
    const int2* __restrict__ eb0, const int2* __restrict__ eb1,
    int* __restrict__ offs0, int* __restrict__ offs1,
    int* __restrict__ csr0, int* __restrict__ csr1) {
    const int b = blockIdx.x, t = threadIdx.x;
    const int* cnt = blockIdx.y ? cnt1 : cnt0;
    const int2* eb = blockIdx.y ? eb1 : eb0;
    int* offs = blockIdx.y ? offs1 : offs0;
    int* csr = blockIdx.y ? csr1 : csr0;
    const int lo = b * NPB;
    const int ncnt = (NN - lo < NPB) ? (NN - lo) : NPB;
    const int beg = cnt[b * NCHUNK];
    const int end = (b == NBKT - 1) ? NE : cnt[(b + 1) * NCHUNK];

    __shared__ int hist[NPB];
    __shared__ int s[512];
    if (t < NPB) hist[t] = 0;
    __syncthreads();
    for (int i = beg + t; i < end; i += 512)
        atomicAdd(&hist[eb[i].y - lo], 1);
    __syncthreads();

    int h = (t < NPB) ? hist[t] : 0;
    s[t] = h;
    __syncthreads();
    for (int off = 1; off < 512; off <<= 1) {
        int a = (t >= off) ? s[t - off] : 0;
        __syncthreads();
        s[t] += a;
        __syncthreads();
    }
    int excl = s[t] - h;
    __syncthreads();
    if (t < NPB) hist[t] = excl;                 // local cursors
    if (t < ncnt) offs[lo + t] = beg + excl;     // final global offsets
    __syncthreads();

    for (int i = beg + t; i < end; i += 512) {
        int2 v = eb[i];
        int pos = atomicAdd(&hist[v.y - lo], 1);
        csr[beg + pos] = v.x;                    // contiguous ~25 KB region per block
    }
}

// ---------------------------------------------------------------------------
// 128x128-tile bf16 MFMA GEMM family, 256 threads (4 waves 2x2), BK=64, K=256,
// DOUBLE-BUFFERED: counted s_waitcnt vmcnt(N) + raw s_barrier keeps next
// K-step's global_load_lds in flight under current MFMA (T3/T4 pattern).
// LDS: As0|As1|Bs0|Bs1 = 4x16KB = 64KB -> 2 blocks/CU. Epilogue reuses smem.
// Both branches via blockIdx.y; XCD-swizzled block decode (col-blocks of a
// row-panel share id mod 8 -> same XCD L2).
// ---------------------------------------------------------------------------

// Generic: C[M, col0..+128) = A[M,256] @ Bt[128r,256]^T (+bias<Nb)(+relu)
// grid (49*16, 2): r8=lid&7, cc=(lid>>3)&1, g=lid>>4.
__global__ __launch_bounds__(256) void mfma_gemm2_kernel(
    const bf16* __restrict__ A0, const bf16* __restrict__ A1,
    const bf16* __restrict__ Bt0, const bf16* __restrict__ Bt1,
    const float* __restrict__ bias0, const float* __restrict__ bias1,
    bf16* __restrict__ out0, bf16* __restrict__ out1,
    int M, int Nb, int do_relu) {
    const int lid = blockIdx.x;
    const int r8 = lid & 7, cc = (lid >> 3) & 1, g = lid >> 4;
    const int row_blk = g * 8 + r8;
    if (row_blk * 128 >= M) return;
    const bf16* A = blockIdx.y ? A1 : A0;
    const bf16* Bt = blockIdx.y ? Bt1 : Bt0;
    const float* bias = blockIdx.y ? bias1 : bias0;
    bf16* out = blockIdx.y ? out1 : out0;

    __shared__ bf16 smem[32768];               // 64KB
    bf16* Asb[2] = {smem, smem + 8192};
    bf16* Bsb[2] = {smem + 16384, smem + 24576};

    const int t    = threadIdx.x;
    const int lane = t & 63;
    const int w    = t >> 6;
    const int row0 = row_blk * 128;
    const int col0 = cc * 128;

    f32x4 acc[4][4] = {};
    const int wm = (w >> 1) * 64, wn = (w & 1) * 64;
    const int fm = lane & 15, fC = lane >> 4;

    stage_tile(A, Asb[0], row0, M - 1, 0, t);
    stage_tile(Bt, Bsb[0], col0, 255, 0, t);
#pragma unroll
    for (int k = 0; k < 4; k++) {
        if (k < 3) {
            stage_tile(A, Asb[(k + 1) & 1], row0, M - 1, (k + 1) * 64, t);
            stage_tile(Bt, Bsb[(k + 1) & 1], col0, 255, (k + 1) * 64, t);
            asm volatile("s_waitcnt vmcnt(8)" ::: "memory");   // cur tile done, next in flight
        } else {
            asm volatile("s_waitcnt vmcnt(0)" ::: "memory");
        }
        __builtin_amdgcn_s_barrier();
        const bf16* cA = Asb[k & 1];
        const bf16* cB = Bsb[k & 1];
#pragma unroll
        for (int s = 0; s < 2; s++) {
            bf16x8 af[4], bfr[4];
#pragma unroll
            for (int i = 0; i < 4; i++) af[i] = frag_ld64(cA, wm + i * 16 + fm, s * 4 + fC);
#pragma unroll
            for (int i = 0; i < 4; i++) bfr[i] = frag_ld64(cB, wn + i * 16 + fm, s * 4 + fC);
#pragma unroll
            for (int i = 0; i < 4; i++)
#pragma unroll
                for (int j = 0; j < 4; j++)
                    acc[i][j] = __builtin_amdgcn_mfma_f32_16x16x32_bf16(af[i], bfr[j], acc[i][j], 0, 0, 0);
        }
        __builtin_amdgcn_s_barrier();
    }

    float bv[4];
#pragma unroll
    for (int j = 0; j < 4; j++) {
        int col = col0 + wn + fm + j * 16;
        bv[j] = (col < Nb) ? bias[col] : 0.f;
    }

#pragma unroll
    for (int p = 0; p < 2; p++) {
        if ((w >> 1) == p) {
#pragma unroll
            for (int i = 0; i < 4; i++)
#pragma unroll
                for (int j = 0; j < 4; j++)
#pragma unroll
                    for (int r2 = 0; r2 < 4; r2++) {
                        int rl = i * 16 + (lane >> 4) * 4 + r2;   // 0..63
                        int cl = wn + fm + j * 16;                // 0..127
                        float v = acc[i][j][r2] + bv[j];
                        if (do_relu) v = fmaxf(v, 0.f);
                        smem[rl * EPI_STRIDE + cl] = (bf16)v;
                    }
        }
        __syncthreads();
#pragma unroll
        for (int q = 0; q < 4; q++) {
            int flat = q * 256 + t;
            int rl = flat >> 4, seg = flat & 15;
            int grow = row0 + p * 64 + rl;
            if (grow < M)
                *(bf16x8*)&out[(size_t)grow * 256 + col0 + seg * 8] =
                    *(const bf16x8*)&smem[rl * EPI_STRIDE + seg * 8];
        }
        __syncthreads();
    }
}

// Fused conv + W|Wr GEMM: A is fp32 X, reg-staged (issue-early / cvt+write-late,
// T14) around the same counted-vmcnt pipeline. Bt2 512x256: cols 0-255 ->
// out_lo (no act), 256-511 -> out_hi = relu(.+bias_hi).
// grid (49*32, 2): r8=lid&7, cc=(lid>>3)&3, g=lid>>5.
__global__ __launch_bounds__(256) void mfma_gemm_fusedconv2_kernel(
    const float* __restrict__ X0, const float* __restrict__ X1,
    const bf16* __restrict__ Bt2_0, const bf16* __restrict__ Bt2_1,
    const float* __restrict__ bh0, const float* __restrict__ bh1,
    bf16* __restrict__ lo0, bf16* __restrict__ lo1,
    bf16* __restrict__ hi0, bf16* __restrict__ hi1, int M) {
    const int lid = blockIdx.x;
    const int r8 = lid & 7, cc = (lid >> 3) & 3, g = lid >> 5;
    const int row_blk = g * 8 + r8;
    if (row_blk * 128 >= M) return;
    const float* Xf = blockIdx.y ? X1 : X0;
    const bf16* Bt2 = blockIdx.y ? Bt2_1 : Bt2_0;
    const float* bias_hi = blockIdx.y ? bh1 : bh0;
    bf16* out_lo = blockIdx.y ? lo1 : lo0;
    bf16* out_hi = blockIdx.y ? hi1 : hi0;

    __shared__ bf16 smem[32768];
    bf16* Asb[2] = {smem, smem + 8192};
    bf16* Bsb[2] = {smem + 16384, smem + 24576};

    const int t    = threadIdx.x;
    const int lane = t & 63;
    const int w    = t >> 6;
    const int row0 = row_blk * 128;
    const int col0 = cc * 128;   // 0..384

    f32x4 acc[4][4] = {};
    const int wm = (w >> 1) * 64, wn = (w & 1) * 64;
    const int fm = lane & 15, fC = lane >> 4;

    float4 ua[4], ub[4];   // in-flight fp32 A fragments (8 float4)
    auto loadA = [&](int k0) {
#pragma unroll
        for (int r = 0; r < 4; r++) {
            int flat = r * 256 + t;
            int fr = flat >> 3, fc = flat & 7;
            int arow = row0 + fr;
            if (arow > M - 1) arow = M - 1;
            const float* gsrc = &Xf[(size_t)arow * 256 + k0 + fc * 8];
            ua[r] = *(const float4*)gsrc;
            ub[r] = *(const float4*)(gsrc + 4);
        }
    };
    auto writeA = [&](bf16* dstA) {
#pragma unroll
        for (int r = 0; r < 4; r++) {
            int flat = r * 256 + t;
            int fr = flat >> 3, fc = flat & 7;
            bf16x8 o;
            o[0] = (bf16)ua[r].x; o[1] = (bf16)ua[r].y; o[2] = (bf16)ua[r].z; o[3] = (bf16)ua[r].w;
            o[4] = (bf16)ub[r].x; o[5] = (bf16)ub[r].y; o[6] = (bf16)ub[r].z; o[7] = (bf16)ub[r].w;
            *(bf16x8*)&dstA[fr * 64 + ((fc ^ ((fr >> 1) & 7)) << 3)] = o;
        }
    };

    // prologue: A(0) regs + B(0) lds-async; cvt+write A(0); B(0) stays in flight
    loadA(0);
    stage_tile(Bt2, Bsb[0], col0, 511, 0, t);
    asm volatile("s_waitcnt vmcnt(4)" ::: "memory");   // A(0) done (B(0) 4 remain)
    writeA(Asb[0]);
    asm volatile("s_waitcnt lgkmcnt(0)" ::: "memory");

#pragma unroll
    for (int k = 0; k < 4; k++) {
        if (k < 3) {
            loadA((k + 1) * 64);                                     // +8 vmem
            stage_tile(Bt2, Bsb[(k + 1) & 1], col0, 511, (k + 1) * 64, t);  // +4
            asm volatile("s_waitcnt vmcnt(12)" ::: "memory");        // B(k) done
        } else {
            asm volatile("s_waitcnt vmcnt(0)" ::: "memory");
        }
        __builtin_amdgcn_s_barrier();
        const bf16* cA = Asb[k & 1];
        const bf16* cB = Bsb[k & 1];
#pragma unroll
        for (int s = 0; s < 2; s++) {
            bf16x8 af[4], bfr[4];
#pragma unroll
            for (int i = 0; i < 4; i++) af[i] = frag_ld64(cA, wm + i * 16 + fm, s * 4 + fC);
#pragma unroll
            for (int i = 0; i < 4; i++) bfr[i] = frag_ld64(cB, wn + i * 16 + fm, s * 4 + fC);
#pragma unroll
            for (int i = 0; i < 4; i++)
#pragma unroll
                for (int j = 0; j < 4; j++)
                    acc[i][j] = __builtin_amdgcn_mfma_f32_16x16x32_bf16(af[i], bfr[j], acc[i][j], 0, 0, 0);
        }
        if (k < 3) {
            asm volatile("s_waitcnt vmcnt(4)" ::: "memory");   // A(k+1) regs ready
            writeA(Asb[(k + 1) & 1]);
            asm volatile("s_waitcnt lgkmcnt(0)" ::: "memory");
        }
        __builtin_amdgcn_s_barrier();
    }

    const bool hi = (col0 >= 256);          // block-uniform
    bf16* out = hi ? out_hi : out_lo;
    const int cb = hi ? col0 - 256 : col0;

    float bv[4];
#pragma unroll
    for (int j = 0; j < 4; j++) {
        int col = cb + wn + fm + j * 16;
        bv[j] = hi ? bias_hi[col] : 0.f;
    }

#pragma unroll
    for (int p = 0; p < 2; p++) {
        if ((w >> 1) == p) {
#pragma unroll
            for (int i = 0; i < 4; i++)
#pragma unroll
                for (int j = 0; j < 4; j++)
#pragma unroll
                    for (int r2 = 0; r2 < 4; r2++) {
                        int rl = i * 16 + (lane >> 4) * 4 + r2;
                        int cl = wn + fm + j * 16;
                        float v = acc[i][j][r2] + bv[j];
                        if (hi) v = fmaxf(v, 0.f);
                        smem[rl * EPI_STRIDE + cl] = (bf16)v;
                    }
        }
        __syncthreads();
#pragma unroll
        for (int q = 0; q < 4; q++) {
            int flat = q * 256 + t;
            int rl = flat >> 4, seg = flat & 15;
            int grow = row0 + p * 64 + rl;
            if (grow < M)
                *(bf16x8*)&out[(size_t)grow * 256 + cb + seg * 8] =
                    *(const bf16x8*)&smem[rl * EPI_STRIDE + seg * 8];
        }
        __syncthreads();
    }
}

// Ro GEMM + per-graph segment reduce fused (no P buffer). grid (49*16, 2).
__global__ __launch_bounds__(256) void mfma_gemm_reduce2_kernel(
    const bf16* __restrict__ A0, const bf16* __restrict__ A1,
    const bf16* __restrict__ Bt0, const bf16* __restrict__ Bt1,
    const float* __restrict__ bias0, const float* __restrict__ bias1,
    const int* __restrict__ gid0, const int* __restrict__ gid1,
    float* __restrict__ G0, float* __restrict__ G1, int M, int Nb) {
    const int lid = blockIdx.x;
    const int r8 = lid & 7, cc = (lid >> 3) & 1, g = lid >> 4;
    const int row_blk = g * 8 + r8;
    if (row_blk * 128 >= M) return;
    const bf16* A = blockIdx.y ? A1 : A0;
    const bf16* Bt = blockIdx.y ? Bt1 : Bt0;
    const float* bias = blockIdx.y ? bias1 : bias0;
    const int* gids = blockIdx.y ? gid1 : gid0;
    float* G = blockIdx.y ? G1 : G0;

    __shared__ bf16 smem[32768];
    bf16* Asb[2] = {smem, smem + 8192};
    bf16* Bsb[2] = {smem + 16384, smem + 24576};

    const int t    = threadIdx.x;
    const int lane = t & 63;
    const int w    = t >> 6;
    const int row0 = row_blk * 128;
    const int col0 = cc * 128;

    f32x4 acc[4][4] = {};
    const int wm = (w >> 1) * 64, wn = (w & 1) * 64;
    const int fm = lane & 15, fC = lane >> 4;

    stage_tile(A, Asb[0], row0, M - 1, 0, t);
    stage_tile(Bt, Bsb[0], col0, 255, 0, t);
#pragma unroll
    for (int k = 0; k < 4; k++) {
        if (k < 3) {
            stage_tile(A, Asb[(k + 1) & 1], row0, M - 1, (k + 1) * 64, t);
            stage_tile(Bt, Bsb[(k + 1) & 1], col0, 255, (k + 1) * 64, t);
            asm volatile("s_waitcnt vmcnt(8)" ::: "memory");
        } else {
            asm volatile("s_waitcnt vmcnt(0)" ::: "memory");
        }
        __builtin_amdgcn_s_barrier();
        const bf16* cA = Asb[k & 1];
        const bf16* cB = Bsb[k & 1];
#pragma unroll
        for (int s = 0; s < 2; s++) {
            bf16x8 af[4], bfr[4];
#pragma unroll
            for (int i = 0; i < 4; i++) af[i] = frag_ld64(cA, wm + i * 16 + fm, s * 4 + fC);
#pragma unroll
            for (int i = 0; i < 4; i++) bfr[i] = frag_ld64(cB, wn + i * 16 + fm, s * 4 + fC);
#pragma unroll
            for (int i = 0; i < 4; i++)
#pragma unroll
                for (int j = 0; j < 4; j++)
                    acc[i][j] = __builtin_amdgcn_mfma_f32_16x16x32_bf16(af[i], bfr[j], acc[i][j], 0, 0, 0);
        }
        __builtin_amdgcn_s_barrier();
    }

    float bv[4];
#pragma unroll
    for (int j = 0; j < 4; j++) {
        int col = col0 + wn + fm + j * 16;
        bv[j] = (col < Nb) ? bias[col] : 0.f;
    }

#pragma unroll
    for (int p = 0; p < 2; p++) {
        if ((w >> 1) == p) {
#pragma unroll
            for (int i = 0; i < 4; i++)
#pragma unroll
                for (int j = 0; j < 4; j++)
#pragma unroll
                    for (int r2 = 0; r2 < 4; r2++) {
                        int rl = i * 16 + (lane >> 4) * 4 + r2;
                        int cl = wn + fm + j * 16;
                        smem[rl * EPI_STRIDE + cl] = (bf16)(acc[i][j][r2] + bv[j]);
                    }
        }
        __syncthreads();
        // segment reduce: 2 threads/column, 32 rows each; sorted gids ->
        // flush partial into G on boundary (fp32 atomic, device scope).
        {
            int c = t & 127, rh = t >> 7;
            int colg = col0 + c;
            if (colg < Nb) {
                float run = 0.f;
                int gprev = -1;
                for (int r = 0; r < 32; r++) {
                    int grow = row0 + p * 64 + rh * 32 + r;
                    if (grow >= M) break;
                    int gg = gids[grow];
                    if (gg != gprev) {
                        if (gprev >= 0) atomicAdd(&G[(size_t)gprev * GFEAT + colg], run);
                        run = 0.f;
                        gprev = gg;
                    }
                    run += (float)smem[(rh * 32 + r) * EPI_STRIDE + c];
                }
                if (gprev >= 0) atomicAdd(&G[(size_t)gprev * GFEAT + colg], run);
            }
        }
        __syncthreads();
    }
}

// ---------------------------------------------------------------------------
// edge aggregation + combine, both branches (blockIdx.y):
// H[v] = relu(sum_{e: dst=v} hW[src[e]] + b) + res[v]
// (memory-system ceiling for this access pattern: ~3.9 TB/s, 3 structures tried)
// ---------------------------------------------------------------------------
__global__ __launch_bounds__(256) void agg_combine2_kernel(
    const bf16* __restrict__ hW0, const bf16* __restrict__ hW1,
    const int* __restrict__ csr0, const int* __restrict__ csr1,
    const int* __restrict__ offs0, const int* __restrict__ offs1,
    const float* __restrict__ bias0, const float* __restrict__ bias1,
    const bf16* __restrict__ res0, const bf16* __restrict__ res1,
    bf16* __restrict__ H0, bf16* __restrict__ H1, int n_nodes) {
    const bf16* hW = blockIdx.y ? hW1 : hW0;
    const int* csr_src = blockIdx.y ? csr1 : csr0;
    const int* offsets = blockIdx.y ? offs1 : offs0;
    const float* bias = blockIdx.y ? bias1 : bias0;
    const bf16* res = blockIdx.y ? res1 : res0;
    bf16* H = blockIdx.y ? H1 : H0;

    int wave = threadIdx.x >> 6;
    int lane = threadIdx.x & 63;
    int node = blockIdx.x * 4 + wave;
    if (node >= n_nodes) return;
    int beg = offsets[node], end = offsets[node + 1];
    const int half = lane >> 5;
    const int fo   = (lane & 31) * 8;

    float acc[8] = {};
    int j = beg;
    for (; j + 6 + half < end; j += 8) {
        int s0 = csr_src[j + half];
        int s1 = csr_src[j + 2 + half];
        int s2 = csr_src[j + 4 + half];
        int s3 = csr_src[j + 6 + half];
        bf16x8 v0 = *(const bf16x8*)&hW[(size_t)s0 * DD + fo];
        bf16x8 v1 = *(const bf16x8*)&hW[(size_t)s1 * DD + fo];
        bf16x8 v2 = *(const bf16x8*)&hW[(size_t)s2 * DD + fo];
        bf16x8 v3 = *(const bf16x8*)&hW[(size_t)s3 * DD + fo];
#pragma unroll
        for (int q = 0; q < 8; q++) acc[q] += (float)v0[q];
#pragma unroll
        for (int q = 0; q < 8; q++) acc[q] += (float)v1[q];
#pragma unroll
        for (int q = 0; q < 8; q++) acc[q] += (float)v2[q];
#pragma unroll
        for (int q = 0; q < 8; q++) acc[q] += (float)v3[q];
    }
    for (; j + half < end; j += 2) {
        int s = csr_src[j + half];
        bf16x8 v = *(const bf16x8*)&hW[(size_t)s * DD + fo];
#pragma unroll
        for (int q = 0; q < 8; q++) acc[q] += (float)v[q];
    }
#pragma unroll
    for (int q = 0; q < 8; q++) acc[q] += __shfl_xor(acc[q], 32, 64);

    if (half == 0) {
        float4 b0 = *(const float4*)&bias[fo];
        float4 b1 = *(const float4*)&bias[fo + 4];
        bf16x8 rv = *(const bf16x8*)&res[(size_t)node * DD + fo];
        bf16x8 o;
        o[0] = (bf16)(fmaxf(acc[0] + b0.x, 0.f) + (float)rv[0]);
        o[1] = (bf16)(fmaxf(acc[1] + b0.y, 0.f) + (float)rv[1]);
        o[2] = (bf16)(fmaxf(acc[2] + b0.z, 0.f) + (float)rv[2]);
        o[3] = (bf16)(fmaxf(acc[3] + b0.w, 0.f) + (float)rv[3]);
        o[4] = (bf16)(fmaxf(acc[4] + b1.x, 0.f) + (float)rv[4]);
        o[5] = (bf16)(fmaxf(acc[5] + b1.y, 0.f) + (float)rv[5]);
        o[6] = (bf16)(fmaxf(acc[6] + b1.z, 0.f) + (float)rv[6]);
        o[7] = (bf16)(fmaxf(acc[7] + b1.w, 0.f) + (float)rv[7]);
        *(bf16x8*)&H[(size_t)node * DD + fo] = o;
    }
}

__global__ __launch_bounds__(256) void predictor_kernel(const float* __restrict__ G1,
                                                        const float* __restrict__ G2,
                                                        const float* __restrict__ Wp,
                                                        const float* __restrict__ bp,
                                                        float* __restrict__ out) {
    int i = blockIdx.x * 256 + threadIdx.x;
    if (i >= NG) return;
    float acc = bp[0];
    for (int f = 0; f < GFEAT; f++)
        acc += (G1[i * GFEAT + f] + G2[i * GFEAT + f]) * Wp[f];
    out[i] = acc;
}

extern "C" void kernel_launch(void* const* d_in, const int* in_sizes, int n_in,
                              void* d_out, int out_size, void* d_ws, size_t ws_size,
                              hipStream_t stream) {
    const float* X1   = (const float*)d_in[0];
    const float* X2   = (const float*)d_in[2];
    const int*   src1 = (const int*)d_in[4];
    const int*   dst1 = (const int*)d_in[5];
    const int*   gid1 = (const int*)d_in[6];
    const int*   src2 = (const int*)d_in[7];
    const int*   dst2 = (const int*)d_in[8];
    const int*   gid2 = (const int*)d_in[9];
    const float* W1  = (const float*)d_in[10]; const float* b1  = (const float*)d_in[11];
    const float* Wr1 = (const float*)d_in[12]; const float* br1 = (const float*)d_in[13];
    const float* W2  = (const float*)d_in[14]; const float* b2  = (const float*)d_in[15];
    const float* Wr2 = (const float*)d_in[16]; const float* br2 = (const float*)d_in[17];
    const float* Ri1 = (const float*)d_in[18]; const float* rbi1 = (const float*)d_in[19];
    const float* Ro1 = (const float*)d_in[20]; const float* rbo1 = (const float*)d_in[21];
    const float* Ri2 = (const float*)d_in[22]; const float* rbi2 = (const float*)d_in[23];
    const float* Ro2 = (const float*)d_in[24]; const float* rbo2 = (const float*)d_in[25];
    const float* Wp  = (const float*)d_in[26]; const float* bp  = (const float*)d_in[27];

    // workspace layout (per-branch buffers; lifetime-disjoint aliases)
    const size_t NB = (size_t)NN * DD * sizeof(bf16);   // 25.6 MB
    char* p = (char*)d_ws;
    bf16* H1   = (bf16*)p; p += NB;     // H (agg->Ri)
    bf16* H2   = (bf16*)p; p += NB;
    bf16* hWR1 = (bf16*)p; p += NB;     // eb1 (CSR), then hW (fused->agg), then R (Ri->Ro)
    bf16* hWR2 = (bf16*)p; p += NB;
    bf16* res1 = (bf16*)p; p += NB;     // res (fused->agg)
    bf16* res2 = (bf16*)p; p += NB;
    float* G1  = (float*)p; p += (size_t)NG * GFEAT * sizeof(float);
    float* G2  = (float*)p; p += (size_t)NG * GFEAT * sizeof(float);
    // 8 weight mats; order: W1,Wr1,Ri1,Ro1,W2,Wr2,Ri2,Ro2 (W|Wr contiguous = fused Bt)
    bf16* Wbase = (bf16*)p; p += 8 * 65536 * sizeof(bf16);
    int* offs1 = (int*)p; p += (NN + 1) * sizeof(int);
    int* offs2 = (int*)p; p += (NN + 1) * sizeof(int);
    int* cnt1  = (int*)p; p += NBKT * NCHUNK * sizeof(int);
    int* cnt2  = (int*)p; p += NBKT * NCHUNK * sizeof(int);
    int* csr1  = (int*)p; p += NE * sizeof(int);
    int* csr2  = (int*)p; p += NE * sizeof(int);
    int2* eb1 = (int2*)hWR1;   // live only during CSR build (before fused writes hW)
    int2* eb2 = (int2*)hWR2;

    zero_g_kernel<<<dim3((NG * GFEAT + 255) / 256, 2), 256, 0, stream>>>(G1, G2);
    conv_w8t_kernel<<<128, 256, 0, stream>>>(W1, Wr1, Ri1, Ro1, W2, Wr2, Ri2, Ro2, Wbase);

    // CSR build (both branches): two-level counting sort, no global atomics
    csr_coarse_hist_kernel<<<dim3(NCHUNK, 2), 256, 0, stream>>>(dst1, dst2, cnt1, cnt2);
    csr_scan_kernel<<<dim3(1, 2), 1024, 0, stream>>>(cnt1, cnt2, offs1, offs2);
    csr_partition_kernel<<<dim3(NCHUNK, 2), 256, 0, stream>>>(
        src1, src2, dst1, dst2, cnt1, cnt2, eb1, eb2);
    csr_bucket_sort_kernel<<<dim3(NBKT, 2), 512, 0, stream>>>(
        cnt1, cnt2, eb1, eb2, offs1, offs2, csr1, csr2);

    // hW = X @ W ; res = relu(X @ Wr + br)   [conv fused into A-staging, dbuf]
    mfma_gemm_fusedconv2_kernel<<<dim3(49 * 32, 2), 256, 0, stream>>>(
        X1, X2, Wbase + 0 * 65536, Wbase + 4 * 65536, br1, br2,
        hWR1, hWR2, res1, res2, NN);
    // H = relu(agg + b) + res
    agg_combine2_kernel<<<dim3((NN + 3) / 4, 2), 256, 0, stream>>>(
        hWR1, hWR2, csr1, csr2, offs1, offs2, b1, b2, res1, res2, H1, H2, NN);
    // R = relu(H @ Ri + rbi)
    mfma_gemm2_kernel<<<dim3(49 * 16, 2), 256, 0, stream>>>(
        H1, H2, Wbase + 2 * 65536, Wbase + 6 * 65536, rbi1, rbi2,
        hWR1, hWR2, NN, DD, 1);
    // G = segment_sum(R @ Ro + rbo) fused
    mfma_gemm_reduce2_kernel<<<dim3(49 * 16, 2), 256, 0, stream>>>(
        hWR1, hWR2, Wbase + 3 * 65536, Wbase + 7 * 65536, rbo1, rbo2,
        gid1, gid2, G1, G2, NN, GFEAT);

    predictor_kernel<<<(NG + 255) / 256, 256, 0, stream>>>(G1, G2, Wp, bp, (float*)d_out);
}